// Round 12
// baseline (728.862 us; speedup 1.0000x reference)
//
#include <hip/hip_runtime.h>

#define ENSN 256
#define XDIM 8192
#define YD 256
#define BATCH 8

// ws layout (float offsets)
#define OFF_Y   0          // [2048][256]            Y = Ens @ H
#define OFF_YC  524288     // [8][256(y)][256(e)]    Yc (transposed, centered)
#define OFF_AUG 1048576    // [8][256][512]          [A | innov] -> [LU | M1]
#define OFF_W   2097152    // [8][256(f)][256(e)]    W = Yc^T M1 / 256
#define OFF_XM  2621440    // [8][8192]              x_m
// scratch reuse:
//   Ht_hi/lo bf16[256][8192] at float-off 524288 / 1572864 (live kc_h..k2m)
//   Wt_hi/lo bf16[8][256][256] at float-off 0 / 262144 (Y region, dead after k3)
//   invU     f32 [8][8][32][32] at OFF_W (W region; dead until k6 writes W)

typedef __attribute__((ext_vector_type(4))) short short4v;
typedef __attribute__((ext_vector_type(8))) short short8v;
typedef __attribute__((ext_vector_type(4))) float float4v;

__device__ __forceinline__ unsigned short f2bf_rne(float x) {
    unsigned u = __float_as_uint(x);
    u += 0x7FFFu + ((u >> 16) & 1u);
    return (unsigned short)(u >> 16);
}

// ---------------- K1: x_m[b][x] = mean_e Ens[b,e,x] ----------------
__global__ __launch_bounds__(256) void k1_colmean(const float* __restrict__ E,
                                                  float* __restrict__ xm) {
    int x = blockIdx.x * 256 + threadIdx.x;
    int b = blockIdx.y;
    const float* p = E + (size_t)b * ENSN * XDIM + x;
    float s = 0.f;
    #pragma unroll 8
    for (int e = 0; e < ENSN; e++) s += p[(size_t)e * XDIM];
    xm[b * XDIM + x] = s * (1.0f / ENSN);
}

// ---------------- KC_H: H[8192][256] -> Ht_hi/lo[256][8192] bf16 (split, transposed) ----------------
__global__ __launch_bounds__(256) void kc_h(const float* __restrict__ H,
                                            short* __restrict__ Hthi,
                                            short* __restrict__ Htlo) {
    __shared__ float T[64][65];
    int k0 = blockIdx.x * 64, n0 = blockIdx.y * 64;
    int tid = threadIdx.x;
    int c = tid & 63, g = tid >> 6;
    #pragma unroll
    for (int p = 0; p < 16; p++)
        T[g + p * 4][c] = H[(size_t)(k0 + g + p * 4) * YD + n0 + c];
    __syncthreads();
    #pragma unroll
    for (int p = 0; p < 16; p++) {
        int nn = g + p * 4;
        float v = T[c][nn];
        unsigned short h = f2bf_rne(v);
        float hf = __uint_as_float(((unsigned)h) << 16);
        unsigned short l2 = f2bf_rne(v - hf);
        Hthi[(size_t)(n0 + nn) * XDIM + k0 + c] = (short)h;
        Htlo[(size_t)(n0 + nn) * XDIM + k0 + c] = (short)l2;
    }
}

// ---------------- K2M: Y = E @ H via bf16-split MFMA ----------------
#define EST 40
#define BST 40

__global__ __launch_bounds__(512, 2) void k2m_ygemm(const float* __restrict__ E,
                                                    const short* __restrict__ Hthi,
                                                    const short* __restrict__ Htlo,
                                                    float* __restrict__ Y) {
    __shared__ __align__(16) short Ehi[64 * EST];
    __shared__ __align__(16) short Elo[64 * EST];
    __shared__ __align__(16) short Bhi[256 * BST];
    __shared__ __align__(16) short Blo[256 * BST];
    int tid = threadIdx.x;
    int lane = tid & 63;
    int w = tid >> 6;                  // wave 0..7
    int m0 = blockIdx.x * 64;
    int kb0 = blockIdx.y * 512;
    int wr = (w & 1) * 32;
    int wc = (w >> 1) * 64;
    float4v acc[8];
    #pragma unroll
    for (int i = 0; i < 8; i++) acc[i] = (float4v){0.f, 0.f, 0.f, 0.f};

    int erow = tid >> 3, ecol = (tid & 7) * 4;
    int brow = tid >> 1, bhalf = (tid & 1) * 16;
    int fr = lane & 15, fg = lane >> 4;

    for (int s = 0; s < 16; s++) {
        int kb = kb0 + s * 32;
        float4 ev = *(const float4*)&E[(size_t)(m0 + erow) * XDIM + kb + ecol];
        float vv[4] = {ev.x, ev.y, ev.z, ev.w};
        short4v hi4, lo4;
        #pragma unroll
        for (int j = 0; j < 4; j++) {
            unsigned short h = f2bf_rne(vv[j]);
            float hf = __uint_as_float(((unsigned)h) << 16);
            unsigned short l2 = f2bf_rne(vv[j] - hf);
            hi4[j] = (short)h; lo4[j] = (short)l2;
        }
        *(short4v*)&Ehi[erow * EST + ecol] = hi4;
        *(short4v*)&Elo[erow * EST + ecol] = lo4;
        short8v bh0 = *(const short8v*)&Hthi[(size_t)brow * XDIM + kb + bhalf];
        short8v bh1 = *(const short8v*)&Hthi[(size_t)brow * XDIM + kb + bhalf + 8];
        short8v bl0 = *(const short8v*)&Htlo[(size_t)brow * XDIM + kb + bhalf];
        short8v bl1 = *(const short8v*)&Htlo[(size_t)brow * XDIM + kb + bhalf + 8];
        *(short8v*)&Bhi[brow * BST + bhalf]     = bh0;
        *(short8v*)&Bhi[brow * BST + bhalf + 8] = bh1;
        *(short8v*)&Blo[brow * BST + bhalf]     = bl0;
        *(short8v*)&Blo[brow * BST + bhalf + 8] = bl1;
        __syncthreads();
        short8v ah[2], al[2], bhf[4], blf[4];
        #pragma unroll
        for (int ti = 0; ti < 2; ti++) {
            ah[ti] = *(const short8v*)&Ehi[(wr + ti * 16 + fr) * EST + fg * 8];
            al[ti] = *(const short8v*)&Elo[(wr + ti * 16 + fr) * EST + fg * 8];
        }
        #pragma unroll
        for (int tj = 0; tj < 4; tj++) {
            bhf[tj] = *(const short8v*)&Bhi[(wc + tj * 16 + fr) * BST + fg * 8];
            blf[tj] = *(const short8v*)&Blo[(wc + tj * 16 + fr) * BST + fg * 8];
        }
        #pragma unroll
        for (int ti = 0; ti < 2; ti++)
            #pragma unroll
            for (int tj = 0; tj < 4; tj++) {
                int a = ti * 4 + tj;
                acc[a] = __builtin_amdgcn_mfma_f32_16x16x32_bf16(ah[ti], bhf[tj], acc[a], 0, 0, 0);
                acc[a] = __builtin_amdgcn_mfma_f32_16x16x32_bf16(ah[ti], blf[tj], acc[a], 0, 0, 0);
                acc[a] = __builtin_amdgcn_mfma_f32_16x16x32_bf16(al[ti], bhf[tj], acc[a], 0, 0, 0);
            }
        __syncthreads();
    }
    #pragma unroll
    for (int ti = 0; ti < 2; ti++)
        #pragma unroll
        for (int tj = 0; tj < 4; tj++)
            #pragma unroll
            for (int q = 0; q < 4; q++) {
                int row = m0 + wr + ti * 16 + fg * 4 + q;
                int col = wc + tj * 16 + fr;
                atomicAdd(&Y[row * YD + col], acc[ti * 4 + tj][q]);
            }
}

// ---------------- K3: y_m, Yc[y][e], innov -> aug right half ----------------
__global__ __launch_bounds__(256) void k3_center(const float* __restrict__ Y,
                                                 const float* __restrict__ ytm,
                                                 const float* __restrict__ ystd,
                                                 const float* __restrict__ noise,
                                                 float* __restrict__ Yc,
                                                 float* __restrict__ aug) {
    int b = blockIdx.y, tid = threadIdx.x;
    int y0 = blockIdx.x * 64;
    __shared__ float red[4][64];
    __shared__ float ym[64], tms[64], s2[64];
    __shared__ float T[64][65];
    int yl = tid & 63, q = tid >> 6;
    float s = 0.f;
    for (int e = q * 64; e < q * 64 + 64; e++)
        s += Y[(size_t)(b * ENSN + e) * YD + y0 + yl];
    red[q][yl] = s;
    __syncthreads();
    if (tid < 64) {
        ym[tid] = (red[0][tid] + red[1][tid] + red[2][tid] + red[3][tid]) * (1.0f / ENSN);
        float sd = ystd[y0 + tid];
        s2[tid] = sd * sd;
        tms[tid] = ytm[y0 + tid];
    }
    __syncthreads();
    for (int e0 = 0; e0 < ENSN; e0 += 64) {
        #pragma unroll
        for (int p = 0; p < 16; p++) {
            int er = q + p * 4;
            T[er][yl] = Y[(size_t)(b * ENSN + e0 + er) * YD + y0 + yl];
        }
        __syncthreads();
        int ec = yl;
        #pragma unroll
        for (int p = 0; p < 16; p++) {
            int yr = q + p * 4;
            int y = y0 + yr, e = e0 + ec;
            float yv = T[ec][yr] - ym[yr];
            Yc[(size_t)b * YD * ENSN + (size_t)y * ENSN + e] = yv;
            aug[(size_t)b * YD * 512 + (size_t)y * 512 + 256 + e] =
                tms[yr] - yv + noise[(size_t)b * YD * ENSN + (size_t)y * ENSN + e] * s2[yr];
        }
        __syncthreads();
    }
}

// ---------------- K4: A = Yc Yc^T / 256 + diag(std^2) -> aug left half ----------------
__global__ __launch_bounds__(256) void k4_cyy(const float* __restrict__ Yc,
                                              const float* __restrict__ ystd,
                                              float* __restrict__ aug) {
    __shared__ float As[16][68];
    __shared__ float Bs[16][68];
    int tid = threadIdx.x;
    int m0 = blockIdx.x * 64, n0 = blockIdx.y * 64, b = blockIdx.z;
    const float* Ycb = Yc + (size_t)b * YD * ENSN;
    int tr = tid >> 4, tc = tid & 15;
    float acc[4][4];
    #pragma unroll
    for (int i = 0; i < 4; i++)
        #pragma unroll
        for (int j = 0; j < 4; j++) acc[i][j] = 0.f;
    int al = tid & 15, am0 = tid >> 4;
    for (int k0 = 0; k0 < ENSN; k0 += 16) {
        #pragma unroll
        for (int p = 0; p < 4; p++) {
            int am = am0 + p * 16;
            As[al][am] = Ycb[(m0 + am) * ENSN + k0 + al];
            Bs[al][am] = Ycb[(n0 + am) * ENSN + k0 + al];
        }
        __syncthreads();
        #pragma unroll
        for (int kk = 0; kk < 16; kk++) {
            float4 a = *(const float4*)&As[kk][tr * 4];
            float4 bb = *(const float4*)&Bs[kk][tc * 4];
            float af[4] = {a.x, a.y, a.z, a.w};
            float bf[4] = {bb.x, bb.y, bb.z, bb.w};
            #pragma unroll
            for (int i = 0; i < 4; i++)
                #pragma unroll
                for (int j = 0; j < 4; j++) acc[i][j] += af[i] * bf[j];
        }
        __syncthreads();
    }
    float* augb = aug + (size_t)b * YD * 512;
    #pragma unroll
    for (int i = 0; i < 4; i++) {
        int u = m0 + tr * 4 + i;
        #pragma unroll
        for (int j = 0; j < 4; j++) {
            int v = n0 + tc * 4 + j;
            float val = acc[i][j] * (1.0f / ENSN);
            if (u == v) { float sv = ystd[u]; val += sv * sv; }
            augb[u * 512 + v] = val;
        }
    }
}

// ---------------- K5p: panel factor for panel p (c0 = 32p) ----------------
// grid = 8 (batch), 1024 threads. NEW: after the wave0 LU, invert L11
// (threads 0-31) and U11 (threads 32-63) in-register -- the panel solves
// then become PARALLEL multiplies (no 32-step serial chains):
//   [U12|Y] = invL11 @ [A12|Z]   (one column per thread, 32 indep accums)
//   L21     = A21 @ invU11       (one row per thread)
// k5p also writes invU[b][p] directly (k5i kernel deleted).
#define RSTP 484
#define LSTP 233

__global__ __launch_bounds__(1024, 4) void k5p_panel(float* __restrict__ aug,
                                                     float* __restrict__ invU, int c0) {
    __shared__ __align__(16) float R[32 * RSTP];
    __shared__ float Ls[32 * LSTP];
    __shared__ __align__(16) float Dg[32 * 33];
    __shared__ float iL[32 * 33];
    __shared__ float iU[32 * 33];
    __shared__ float invd[32];
    int b = blockIdx.x, tid = threadIdx.x;
    float* A = aug + (size_t)b * 256 * 512;
    int r5 = tid >> 5, c5 = tid & 31;
    int WR = 480 - c0;
    int W2 = 224 - c0;

    Dg[r5 * 33 + c5] = A[(c0 + r5) * 512 + c0 + c5];
    __syncthreads();
    // wave0: in-register LU of the 32x32 diag block
    if (tid < 32) {
        float u[32];
        #pragma unroll
        for (int c = 0; c < 32; c++) u[c] = Dg[tid * 33 + c];
        for (int j = 0; j < 31; j++) {
            float pv = __shfl(u[j], j);
            float f = u[j] / pv;
            #pragma unroll
            for (int c = 0; c < 32; c++) {
                if (c > j) {
                    float ujc = __shfl(u[c], j);
                    if (tid > j) u[c] -= f * ujc;
                }
            }
            if (tid > j) u[j] = f;
        }
        #pragma unroll
        for (int c = 0; c < 32; c++) Dg[tid * 33 + c] = u[c];
        invd[tid] = 1.0f / u[tid];
    }
    // stage right block + A21 panel (overlaps wave0 LU)
    for (int cc = c5; cc < WR; cc += 32)
        R[r5 * RSTP + cc] = A[(c0 + r5) * 512 + c0 + 32 + cc];
    for (int row = r5; row < W2; row += 32)
        Ls[c5 * LSTP + row] = A[(c0 + 32 + row) * 512 + c0 + c5];
    __syncthreads();
    // write factored diag back (k5s reads the U strip)
    A[(c0 + r5) * 512 + c0 + c5] = Dg[r5 * 33 + c5];
    // invert L11 (lanes 0-31) and U11 (lanes 32-63); per-lane chains only
    if (tid < 32) {
        int c = tid;
        float x[32];
        #pragma unroll
        for (int j = 0; j < 32; j++) {
            float s = (j == c) ? 1.0f : 0.0f;
            #pragma unroll
            for (int m = 0; m < 32; m++)
                if (m < j) s -= Dg[j * 33 + m] * x[m];
            x[j] = s;             // rows j<c provably 0
        }
        #pragma unroll
        for (int j = 0; j < 32; j++) iL[j * 33 + c] = x[j];
    } else if (tid < 64) {
        int c = tid - 32;
        float x[32];
        #pragma unroll
        for (int j = 31; j >= 0; j--) {
            float s = (j == c) ? 1.0f : 0.0f;
            #pragma unroll
            for (int m = 0; m < 32; m++)
                if (m > j) s -= Dg[j * 33 + m] * x[m];
            x[j] = s * invd[j];   // rows j>c provably 0
        }
        #pragma unroll
        for (int j = 0; j < 32; j++) iU[j * 33 + c] = x[j];
        float* op = invU + (size_t)(b * 8 + (c0 >> 5)) * 1024;
        #pragma unroll
        for (int j = 0; j < 32; j++) op[j * 32 + c] = x[j];
    }
    __syncthreads();
    // [U12|Y] = invL @ R : one column per thread, 32 independent accumulators
    if (tid < WR) {
        float rv[32];
        #pragma unroll
        for (int m = 0; m < 32; m++) rv[m] = R[m * RSTP + tid];
        #pragma unroll
        for (int j = 0; j < 32; j++) {
            const float* lj = &iL[j * 33];
            float s0 = 0.f, s1 = 0.f, s2 = 0.f, s3 = 0.f;
            #pragma unroll
            for (int m = 0; m < 32; m += 4) {
                s0 += lj[m + 0] * rv[m + 0];
                s1 += lj[m + 1] * rv[m + 1];
                s2 += lj[m + 2] * rv[m + 2];
                s3 += lj[m + 3] * rv[m + 3];
            }
            A[(c0 + j) * 512 + c0 + 32 + tid] = (s0 + s1) + (s2 + s3);
        }
    }
    // L21 = A21 @ invU : one row per thread (waves 8-15)
    if (tid >= 512 && tid < 512 + W2) {
        int row = tid - 512;
        float av[32];
        #pragma unroll
        for (int m = 0; m < 32; m++) av[m] = Ls[m * LSTP + row];
        float l[32];
        #pragma unroll
        for (int j = 0; j < 32; j++) {
            float s0 = 0.f, s1 = 0.f, s2 = 0.f, s3 = 0.f;
            #pragma unroll
            for (int m = 0; m < 32; m += 4) {
                s0 += av[m + 0] * iU[(m + 0) * 33 + j];
                s1 += av[m + 1] * iU[(m + 1) * 33 + j];
                s2 += av[m + 2] * iU[(m + 2) * 33 + j];
                s3 += av[m + 3] * iU[(m + 3) * 33 + j];
            }
            l[j] = (s0 + s1) + (s2 + s3);
        }
        #pragma unroll
        for (int j = 0; j < 32; j++)
            Ls[j * LSTP + row] = l[j];
    }
    __syncthreads();
    for (int row = r5; row < W2; row += 32)
        A[(c0 + 32 + row) * 512 + c0 + c5] = Ls[c5 * LSTP + row];
}

// ---------------- K5t: trailing update [A22|Z] -= L21 * [U12|Y] ----------------
__global__ __launch_bounds__(256) void k5t_trail(float* __restrict__ aug, int c0) {
    __shared__ __align__(16) float Lt[32][36];
    __shared__ __align__(16) float Ut[32][36];
    int b = blockIdx.z, tid = threadIdx.x;
    float* A = aug + (size_t)b * 256 * 512;
    int r0  = c0 + 32 + blockIdx.x * 32;
    int cc0 = c0 + 32 + blockIdx.y * 32;
    int lr = tid >> 3, lc = (tid & 7) * 4;
    *(float4*)&Lt[lr][lc] = *(const float4*)&A[(size_t)(r0 + lr) * 512 + c0 + lc];
    *(float4*)&Ut[lr][lc] = *(const float4*)&A[(size_t)(c0 + lr) * 512 + cc0 + lc];
    __syncthreads();
    float* gp = &A[(size_t)(r0 + lr) * 512 + cc0 + lc];
    float4 acc = *(const float4*)gp;
    #pragma unroll
    for (int k = 0; k < 32; k++) {
        float lv = Lt[lr][k];
        float4 uv = *(const float4*)&Ut[k][lc];
        acc.x -= lv * uv.x;
        acc.y -= lv * uv.y;
        acc.z -= lv * uv.z;
        acc.w -= lv * uv.w;
    }
    *(float4*)gp = acc;
}

// ---------------- K5s: backward sweep via X = invU * Z, 32 cols/block ----------------
// grid (8 colblk, 8 batch) = 64 blocks, 512 threads (16 groups x 32 cols).
// Parallel invU-multiply per panel; no serial chains anywhere.
#define ZST  36
#define LBST 36

__global__ __launch_bounds__(512, 2) void k5s_solve(float* __restrict__ aug,
                                                    const float* __restrict__ invU) {
    __shared__ __align__(16) float Zs[256 * ZST];
    __shared__ __align__(16) float Lb[224 * LBST];
    __shared__ __align__(16) float Dg[32 * 33];
    int b = blockIdx.y, tid = threadIdx.x;
    float* A = aug + (size_t)b * 256 * 512;
    int cb = blockIdx.x * 32;
    int c = tid & 31, g = tid >> 5;       // g in 0..15
    int rr = tid >> 5, cc = tid & 31;

    for (int r = g; r < 256; r += 16)
        Zs[r * ZST + c] = A[r * 512 + 256 + cb + c];

    for (int p = 7; p >= 0; p--) {
        int c0 = 32 * p, na = c0;
        for (int i = tid; i < 1024; i += 512)
            Dg[(i >> 5) * 33 + (i & 31)] = invU[(size_t)(b * 8 + p) * 1024 + i];
        for (int r = rr; r < na; r += 16)
            Lb[r * LBST + cc] = A[r * 512 + c0 + cc];
        __syncthreads();
        // X = invU * Z  (each group: 2 rows x 32 cols)
        float z[32];
        #pragma unroll
        for (int m = 0; m < 32; m++) z[m] = Zs[(c0 + m) * ZST + c];
        float xr[2];
        #pragma unroll
        for (int r2 = 0; r2 < 2; r2++) {
            const float* dr = &Dg[(g * 2 + r2) * 33];
            float s0 = 0.f, s1 = 0.f, s2 = 0.f, s3 = 0.f;
            #pragma unroll
            for (int m = 0; m < 32; m += 4) {
                s0 += dr[m + 0] * z[m + 0];
                s1 += dr[m + 1] * z[m + 1];
                s2 += dr[m + 2] * z[m + 2];
                s3 += dr[m + 3] * z[m + 3];
            }
            xr[r2] = (s0 + s1) + (s2 + s3);
        }
        __syncthreads();
        #pragma unroll
        for (int r2 = 0; r2 < 2; r2++)
            Zs[(c0 + g * 2 + r2) * ZST + c] = xr[r2];
        __syncthreads();
        if (na > 0) {
            float zx[32];
            #pragma unroll
            for (int k = 0; k < 32; k++) zx[k] = Zs[(c0 + k) * ZST + c];
            for (int r = g; r < na; r += 16) {
                const float* lp = &Lb[r * LBST];
                float a0 = 0.f, a1 = 0.f, a2 = 0.f, a3 = 0.f;
                #pragma unroll
                for (int k = 0; k < 32; k += 4) {
                    float4 lv = *(const float4*)(lp + k);
                    a0 += lv.x * zx[k + 0];
                    a1 += lv.y * zx[k + 1];
                    a2 += lv.z * zx[k + 2];
                    a3 += lv.w * zx[k + 3];
                }
                Zs[r * ZST + c] -= (a0 + a1) + (a2 + a3);
            }
        }
        __syncthreads();
    }

    for (int r = g; r < 256; r += 16)
        A[r * 512 + 256 + cb + c] = Zs[r * ZST + c];
}

// ---------------- K6: W[f][e] = sum_y Yc[y][f] * M1[y][e] / 256 ----------------
__global__ __launch_bounds__(256) void k6_w(const float* __restrict__ Yc,
                                            const float* __restrict__ aug,
                                            float* __restrict__ W) {
    __shared__ float As[16][68];
    __shared__ float Bs[16][68];
    int tid = threadIdx.x;
    int m0 = blockIdx.x * 64, n0 = blockIdx.y * 64, b = blockIdx.z;
    const float* Ycb = Yc + (size_t)b * YD * ENSN;
    const float* augb = aug + (size_t)b * YD * 512;
    int tr = tid >> 4, tc = tid & 15;
    float acc[4][4];
    #pragma unroll
    for (int i = 0; i < 4; i++)
        #pragma unroll
        for (int j = 0; j < 4; j++) acc[i][j] = 0.f;
    int c = tid & 63, kr0 = tid >> 6;
    for (int k0 = 0; k0 < YD; k0 += 16) {
        #pragma unroll
        for (int p = 0; p < 4; p++) {
            int kk = kr0 + p * 4;
            As[kk][c] = Ycb[(k0 + kk) * ENSN + m0 + c];
            Bs[kk][c] = augb[(k0 + kk) * 512 + 256 + n0 + c];
        }
        __syncthreads();
        #pragma unroll
        for (int kk = 0; kk < 16; kk++) {
            float4 a = *(const float4*)&As[kk][tr * 4];
            float4 bb = *(const float4*)&Bs[kk][tc * 4];
            float af[4] = {a.x, a.y, a.z, a.w};
            float bf[4] = {bb.x, bb.y, bb.z, bb.w};
            #pragma unroll
            for (int i = 0; i < 4; i++)
                #pragma unroll
                for (int j = 0; j < 4; j++) acc[i][j] += af[i] * bf[j];
        }
        __syncthreads();
    }
    float* Wb = W + (size_t)b * ENSN * ENSN;
    #pragma unroll
    for (int i = 0; i < 4; i++)
        #pragma unroll
        for (int j = 0; j < 4; j++)
            Wb[(m0 + tr * 4 + i) * ENSN + n0 + tc * 4 + j] = acc[i][j] * (1.0f / ENSN);
}

// ---------------- KW_W: W[f][e] -> Wt_hi/lo[e][f] bf16 (split, transposed) ----------------
__global__ __launch_bounds__(256) void kw_w(const float* __restrict__ W,
                                            short* __restrict__ Wthi,
                                            short* __restrict__ Wtlo) {
    __shared__ float T[64][65];
    int f0 = blockIdx.x * 64, e0 = blockIdx.y * 64, b = blockIdx.z;
    const float* Wb = W + (size_t)b * ENSN * ENSN;
    int tid = threadIdx.x;
    int c = tid & 63, g = tid >> 6;
    #pragma unroll
    for (int p = 0; p < 16; p++)
        T[g + p * 4][c] = Wb[(size_t)(f0 + g + p * 4) * ENSN + e0 + c];
    __syncthreads();
    #pragma unroll
    for (int p = 0; p < 16; p++) {
        int ee = g + p * 4;
        float v = T[c][ee];   // = W[f0+c][e0+ee]
        unsigned short h = f2bf_rne(v);
        float hf = __uint_as_float(((unsigned)h) << 16);
        unsigned short l2 = f2bf_rne(v - hf);
        size_t o = (size_t)b * ENSN * ENSN + (size_t)(e0 + ee) * ENSN + f0 + c;
        Wthi[o] = (short)h;
        Wtlo[o] = (short)l2;
    }
}

// ---------------- K7M: out = E + Wt^T-style MFMA update ----------------
#define WST 36
#define XST 36

__global__ __launch_bounds__(512, 2) void k7m_update(const float* __restrict__ E,
                                                     const short* __restrict__ Wthi,
                                                     const short* __restrict__ Wtlo,
                                                     const float* __restrict__ xm,
                                                     float* __restrict__ out) {
    __shared__ __align__(16) short Ahi[256 * WST];
    __shared__ __align__(16) short Alo[256 * WST];
    __shared__ __align__(16) short Bhi[64 * XST];
    __shared__ __align__(16) short Blo[64 * XST];
    __shared__ float xs[64];
    int tid = threadIdx.x;
    int lane = tid & 63;
    int w = tid >> 6;
    int x0 = blockIdx.x * 64;
    int b = blockIdx.y;
    const short* Whb = Wthi + (size_t)b * ENSN * ENSN;
    const short* Wlb = Wtlo + (size_t)b * ENSN * ENSN;
    const float* Eb = E + (size_t)b * ENSN * XDIM;
    if (tid < 64) xs[tid] = xm[b * XDIM + x0 + tid];
    __syncthreads();
    int wr = (w & 3) * 64;    // wave M offset (e)
    int wc = (w >> 2) * 32;   // wave N offset (x)
    float4v acc[8];
    #pragma unroll
    for (int i = 0; i < 8; i++) acc[i] = (float4v){0.f, 0.f, 0.f, 0.f};
    int fr = lane & 15, fg = lane >> 4;
    int ae = tid >> 2, ach = (tid & 3) * 8;   // A stage: 2 rows of 128 e
    int bx = tid & 63, bkq = tid >> 6;        // B stage: 4 k per thread

    for (int s = 0; s < 8; s++) {
        int k0 = s * 32;
        #pragma unroll
        for (int h = 0; h < 2; h++) {
            int e = ae + h * 128;
            *(short8v*)&Ahi[e * WST + ach] = *(const short8v*)&Whb[(size_t)e * ENSN + k0 + ach];
            *(short8v*)&Alo[e * WST + ach] = *(const short8v*)&Wlb[(size_t)e * ENSN + k0 + ach];
        }
        short4v hi4, lo4;
        #pragma unroll
        for (int j = 0; j < 4; j++) {
            float v = Eb[(size_t)(k0 + bkq * 4 + j) * XDIM + x0 + bx] - xs[bx];
            unsigned short h = f2bf_rne(v);
            float hf = __uint_as_float(((unsigned)h) << 16);
            unsigned short l2 = f2bf_rne(v - hf);
            hi4[j] = (short)h; lo4[j] = (short)l2;
        }
        *(short4v*)&Bhi[bx * XST + bkq * 4] = hi4;
        *(short4v*)&Blo[bx * XST + bkq * 4] = lo4;
        __syncthreads();
        short8v ah[4], al[4], bhf[2], blf[2];
        #pragma unroll
        for (int ti = 0; ti < 4; ti++) {
            ah[ti] = *(const short8v*)&Ahi[(wr + ti * 16 + fr) * WST + fg * 8];
            al[ti] = *(const short8v*)&Alo[(wr + ti * 16 + fr) * WST + fg * 8];
        }
        #pragma unroll
        for (int tj = 0; tj < 2; tj++) {
            bhf[tj] = *(const short8v*)&Bhi[(wc + tj * 16 + fr) * XST + fg * 8];
            blf[tj] = *(const short8v*)&Blo[(wc + tj * 16 + fr) * XST + fg * 8];
        }
        #pragma unroll
        for (int ti = 0; ti < 4; ti++)
            #pragma unroll
            for (int tj = 0; tj < 2; tj++) {
                int a = ti * 2 + tj;
                acc[a] = __builtin_amdgcn_mfma_f32_16x16x32_bf16(ah[ti], bhf[tj], acc[a], 0, 0, 0);
                acc[a] = __builtin_amdgcn_mfma_f32_16x16x32_bf16(ah[ti], blf[tj], acc[a], 0, 0, 0);
                acc[a] = __builtin_amdgcn_mfma_f32_16x16x32_bf16(al[ti], bhf[tj], acc[a], 0, 0, 0);
            }
        __syncthreads();
    }
    #pragma unroll
    for (int ti = 0; ti < 4; ti++)
        #pragma unroll
        for (int tj = 0; tj < 2; tj++)
            #pragma unroll
            for (int q = 0; q < 4; q++) {
                int e = wr + ti * 16 + fg * 4 + q;
                int x = x0 + wc + tj * 16 + fr;
                size_t idx = (size_t)(b * ENSN + e) * XDIM + x;
                out[idx] = E[idx] + acc[ti * 2 + tj][q];
            }
}

extern "C" void kernel_launch(void* const* d_in, const int* in_sizes, int n_in,
                              void* d_out, int out_size, void* d_ws, size_t ws_size,
                              hipStream_t stream) {
    const float* Ens   = (const float*)d_in[0];  // [8,256,8192]
    const float* H     = (const float*)d_in[1];  // [8192,256]
    const float* ytm   = (const float*)d_in[2];  // [1,256]
    const float* ystd  = (const float*)d_in[3];  // [1,256]
    const float* noise = (const float*)d_in[4];  // [8,256,256]
    float* out = (float*)d_out;
    float* ws  = (float*)d_ws;

    float* Y   = ws + OFF_Y;
    float* Yc  = ws + OFF_YC;
    float* aug = ws + OFF_AUG;
    float* W   = ws + OFF_W;
    float* xm  = ws + OFF_XM;
    // bf16-split transposed H (Yc/aug span; dead once k2m finishes)
    short* Hthi = (short*)(ws + 524288);    // 256x8192 bf16
    short* Htlo = (short*)(ws + 1572864);   // 256x8192 bf16
    // bf16-split transposed W (Y span; Y is dead after k3)
    short* Wthi = (short*)(ws + 0);         // 8x256x256 bf16 = 262144 floats
    short* Wtlo = (short*)(ws + 262144);    // 8x256x256 bf16
    // invU in the W region (dead until k6 writes W): 8*8*1024 = 65536 floats
    float* invU = ws + OFF_W;

    hipMemsetAsync(Y, 0, (size_t)2048 * 256 * sizeof(float), stream);

    k1_colmean<<<dim3(XDIM / 256, BATCH), 256, 0, stream>>>(Ens, xm);
    kc_h<<<dim3(XDIM / 64, YD / 64), 256, 0, stream>>>(H, Hthi, Htlo);
    k2m_ygemm<<<dim3(2048 / 64, 16), 512, 0, stream>>>(Ens, Hthi, Htlo, Y);
    k3_center<<<dim3(4, BATCH), 256, 0, stream>>>(Y, ytm, ystd, noise, Yc, aug);
    k4_cyy<<<dim3(4, 4, BATCH), 256, 0, stream>>>(Yc, ystd, aug);
    for (int p = 0; p < 8; p++) {
        k5p_panel<<<dim3(BATCH), 1024, 0, stream>>>(aug, invU, 32 * p);
        if (p < 7)
            k5t_trail<<<dim3(7 - p, 15 - p, BATCH), 256, 0, stream>>>(aug, 32 * p);
    }
    k5s_solve<<<dim3(8, BATCH), 512, 0, stream>>>(aug, invU);
    k6_w<<<dim3(4, 4, BATCH), 256, 0, stream>>>(Yc, aug, W);
    kw_w<<<dim3(4, 4, BATCH), 256, 0, stream>>>(W, Wthi, Wtlo);
    k7m_update<<<dim3(XDIM / 64, BATCH), 512, 0, stream>>>(Ens, Wthi, Wtlo, xm, out);
}

// Round 13
// 644.452 us; speedup vs baseline: 1.1310x; 1.1310x over previous
//
#include <hip/hip_runtime.h>

#define ENSN 256
#define XDIM 8192
#define YD 256
#define BATCH 8

// ws layout (float offsets)
#define OFF_Y   0          // [2048][256]            Y = Ens @ H
#define OFF_YC  524288     // [8][256(y)][256(e)]    Yc (transposed, centered)
#define OFF_AUG 1048576    // [8][256][512]          [A | innov] -> [LU | M1]
#define OFF_W   2097152    // [8][256(f)][256(e)]    W = Yc^T M1 / 256
#define OFF_XM  2621440    // [8][8192]              x_m
// scratch reuse:
//   Ht_hi/lo bf16[256][8192] at float-off 524288 / 1572864 (live kc_h..k2m)
//   Wt_hi/lo bf16[8][256][256] at float-off 0 / 262144 (Y region, dead after k3)
//   invU     f32 [8][8][32][32] at OFF_W (W region; dead until k6 writes W)

typedef __attribute__((ext_vector_type(4))) short short4v;
typedef __attribute__((ext_vector_type(8))) short short8v;
typedef __attribute__((ext_vector_type(4))) float float4v;

__device__ __forceinline__ unsigned short f2bf_rne(float x) {
    unsigned u = __float_as_uint(x);
    u += 0x7FFFu + ((u >> 16) & 1u);
    return (unsigned short)(u >> 16);
}

// ---------------- K1: x_m[b][x] = mean_e Ens[b,e,x] ----------------
__global__ __launch_bounds__(256) void k1_colmean(const float* __restrict__ E,
                                                  float* __restrict__ xm) {
    int x = blockIdx.x * 256 + threadIdx.x;
    int b = blockIdx.y;
    const float* p = E + (size_t)b * ENSN * XDIM + x;
    float s = 0.f;
    #pragma unroll 8
    for (int e = 0; e < ENSN; e++) s += p[(size_t)e * XDIM];
    xm[b * XDIM + x] = s * (1.0f / ENSN);
}

// ---------------- KC_H: H[8192][256] -> Ht_hi/lo[256][8192] bf16 (split, transposed) ----------------
__global__ __launch_bounds__(256) void kc_h(const float* __restrict__ H,
                                            short* __restrict__ Hthi,
                                            short* __restrict__ Htlo) {
    __shared__ float T[64][65];
    int k0 = blockIdx.x * 64, n0 = blockIdx.y * 64;
    int tid = threadIdx.x;
    int c = tid & 63, g = tid >> 6;
    #pragma unroll
    for (int p = 0; p < 16; p++)
        T[g + p * 4][c] = H[(size_t)(k0 + g + p * 4) * YD + n0 + c];
    __syncthreads();
    #pragma unroll
    for (int p = 0; p < 16; p++) {
        int nn = g + p * 4;
        float v = T[c][nn];
        unsigned short h = f2bf_rne(v);
        float hf = __uint_as_float(((unsigned)h) << 16);
        unsigned short l2 = f2bf_rne(v - hf);
        Hthi[(size_t)(n0 + nn) * XDIM + k0 + c] = (short)h;
        Htlo[(size_t)(n0 + nn) * XDIM + k0 + c] = (short)l2;
    }
}

// ---------------- K2M: Y = E @ H via bf16-split MFMA ----------------
// B-staging restaged 16-rows-per-wave (2 passes): the old 32-rows-per-wave
// pattern hit 4-way LDS store conflicts (row stride 20 dwords, period 8
// mod 32) -> 5.77M SQ_LDS_BANK_CONFLICT. Frag reads stay 2-way (free).
#define EST 40
#define BST 40

__global__ __launch_bounds__(512, 2) void k2m_ygemm(const float* __restrict__ E,
                                                    const short* __restrict__ Hthi,
                                                    const short* __restrict__ Htlo,
                                                    float* __restrict__ Y) {
    __shared__ __align__(16) short Ehi[64 * EST];
    __shared__ __align__(16) short Elo[64 * EST];
    __shared__ __align__(16) short Bhi[256 * BST];
    __shared__ __align__(16) short Blo[256 * BST];
    int tid = threadIdx.x;
    int lane = tid & 63;
    int w = tid >> 6;                  // wave 0..7
    int m0 = blockIdx.x * 64;
    int kb0 = blockIdx.y * 512;
    int wr = (w & 1) * 32;
    int wc = (w >> 1) * 64;
    float4v acc[8];
    #pragma unroll
    for (int i = 0; i < 8; i++) acc[i] = (float4v){0.f, 0.f, 0.f, 0.f};

    int erow = tid >> 3, ecol = (tid & 7) * 4;
    int brow4 = tid >> 2, bch = (tid & 3) * 8;   // 4 lanes/row -> 16 rows/wave
    int fr = lane & 15, fg = lane >> 4;

    for (int s = 0; s < 16; s++) {
        int kb = kb0 + s * 32;
        float4 ev = *(const float4*)&E[(size_t)(m0 + erow) * XDIM + kb + ecol];
        float vv[4] = {ev.x, ev.y, ev.z, ev.w};
        short4v hi4, lo4;
        #pragma unroll
        for (int j = 0; j < 4; j++) {
            unsigned short h = f2bf_rne(vv[j]);
            float hf = __uint_as_float(((unsigned)h) << 16);
            unsigned short l2 = f2bf_rne(vv[j] - hf);
            hi4[j] = (short)h; lo4[j] = (short)l2;
        }
        *(short4v*)&Ehi[erow * EST + ecol] = hi4;
        *(short4v*)&Elo[erow * EST + ecol] = lo4;
        #pragma unroll
        for (int pass = 0; pass < 2; pass++) {
            int rowb = brow4 + pass * 128;
            *(short8v*)&Bhi[rowb * BST + bch] =
                *(const short8v*)&Hthi[(size_t)rowb * XDIM + kb + bch];
            *(short8v*)&Blo[rowb * BST + bch] =
                *(const short8v*)&Htlo[(size_t)rowb * XDIM + kb + bch];
        }
        __syncthreads();
        short8v ah[2], al[2], bhf[4], blf[4];
        #pragma unroll
        for (int ti = 0; ti < 2; ti++) {
            ah[ti] = *(const short8v*)&Ehi[(wr + ti * 16 + fr) * EST + fg * 8];
            al[ti] = *(const short8v*)&Elo[(wr + ti * 16 + fr) * EST + fg * 8];
        }
        #pragma unroll
        for (int tj = 0; tj < 4; tj++) {
            bhf[tj] = *(const short8v*)&Bhi[(wc + tj * 16 + fr) * BST + fg * 8];
            blf[tj] = *(const short8v*)&Blo[(wc + tj * 16 + fr) * BST + fg * 8];
        }
        #pragma unroll
        for (int ti = 0; ti < 2; ti++)
            #pragma unroll
            for (int tj = 0; tj < 4; tj++) {
                int a = ti * 4 + tj;
                acc[a] = __builtin_amdgcn_mfma_f32_16x16x32_bf16(ah[ti], bhf[tj], acc[a], 0, 0, 0);
                acc[a] = __builtin_amdgcn_mfma_f32_16x16x32_bf16(ah[ti], blf[tj], acc[a], 0, 0, 0);
                acc[a] = __builtin_amdgcn_mfma_f32_16x16x32_bf16(al[ti], bhf[tj], acc[a], 0, 0, 0);
            }
        __syncthreads();
    }
    #pragma unroll
    for (int ti = 0; ti < 2; ti++)
        #pragma unroll
        for (int tj = 0; tj < 4; tj++)
            #pragma unroll
            for (int q = 0; q < 4; q++) {
                int row = m0 + wr + ti * 16 + fg * 4 + q;
                int col = wc + tj * 16 + fr;
                atomicAdd(&Y[row * YD + col], acc[ti * 4 + tj][q]);
            }
}

// ---------------- K3: y_m, Yc[y][e], innov -> aug right half ----------------
__global__ __launch_bounds__(256) void k3_center(const float* __restrict__ Y,
                                                 const float* __restrict__ ytm,
                                                 const float* __restrict__ ystd,
                                                 const float* __restrict__ noise,
                                                 float* __restrict__ Yc,
                                                 float* __restrict__ aug) {
    int b = blockIdx.y, tid = threadIdx.x;
    int y0 = blockIdx.x * 64;
    __shared__ float red[4][64];
    __shared__ float ym[64], tms[64], s2[64];
    __shared__ float T[64][65];
    int yl = tid & 63, q = tid >> 6;
    float s = 0.f;
    for (int e = q * 64; e < q * 64 + 64; e++)
        s += Y[(size_t)(b * ENSN + e) * YD + y0 + yl];
    red[q][yl] = s;
    __syncthreads();
    if (tid < 64) {
        ym[tid] = (red[0][tid] + red[1][tid] + red[2][tid] + red[3][tid]) * (1.0f / ENSN);
        float sd = ystd[y0 + tid];
        s2[tid] = sd * sd;
        tms[tid] = ytm[y0 + tid];
    }
    __syncthreads();
    for (int e0 = 0; e0 < ENSN; e0 += 64) {
        #pragma unroll
        for (int p = 0; p < 16; p++) {
            int er = q + p * 4;
            T[er][yl] = Y[(size_t)(b * ENSN + e0 + er) * YD + y0 + yl];
        }
        __syncthreads();
        int ec = yl;
        #pragma unroll
        for (int p = 0; p < 16; p++) {
            int yr = q + p * 4;
            int y = y0 + yr, e = e0 + ec;
            float yv = T[ec][yr] - ym[yr];
            Yc[(size_t)b * YD * ENSN + (size_t)y * ENSN + e] = yv;
            aug[(size_t)b * YD * 512 + (size_t)y * 512 + 256 + e] =
                tms[yr] - yv + noise[(size_t)b * YD * ENSN + (size_t)y * ENSN + e] * s2[yr];
        }
        __syncthreads();
    }
}

// ---------------- K4: A = Yc Yc^T / 256 + diag(std^2) -> aug left half ----------------
__global__ __launch_bounds__(256) void k4_cyy(const float* __restrict__ Yc,
                                              const float* __restrict__ ystd,
                                              float* __restrict__ aug) {
    __shared__ float As[16][68];
    __shared__ float Bs[16][68];
    int tid = threadIdx.x;
    int m0 = blockIdx.x * 64, n0 = blockIdx.y * 64, b = blockIdx.z;
    const float* Ycb = Yc + (size_t)b * YD * ENSN;
    int tr = tid >> 4, tc = tid & 15;
    float acc[4][4];
    #pragma unroll
    for (int i = 0; i < 4; i++)
        #pragma unroll
        for (int j = 0; j < 4; j++) acc[i][j] = 0.f;
    int al = tid & 15, am0 = tid >> 4;
    for (int k0 = 0; k0 < ENSN; k0 += 16) {
        #pragma unroll
        for (int p = 0; p < 4; p++) {
            int am = am0 + p * 16;
            As[al][am] = Ycb[(m0 + am) * ENSN + k0 + al];
            Bs[al][am] = Ycb[(n0 + am) * ENSN + k0 + al];
        }
        __syncthreads();
        #pragma unroll
        for (int kk = 0; kk < 16; kk++) {
            float4 a = *(const float4*)&As[kk][tr * 4];
            float4 bb = *(const float4*)&Bs[kk][tc * 4];
            float af[4] = {a.x, a.y, a.z, a.w};
            float bf[4] = {bb.x, bb.y, bb.z, bb.w};
            #pragma unroll
            for (int i = 0; i < 4; i++)
                #pragma unroll
                for (int j = 0; j < 4; j++) acc[i][j] += af[i] * bf[j];
        }
        __syncthreads();
    }
    float* augb = aug + (size_t)b * YD * 512;
    #pragma unroll
    for (int i = 0; i < 4; i++) {
        int u = m0 + tr * 4 + i;
        #pragma unroll
        for (int j = 0; j < 4; j++) {
            int v = n0 + tc * 4 + j;
            float val = acc[i][j] * (1.0f / ENSN);
            if (u == v) { float sv = ystd[u]; val += sv * sv; }
            augb[u * 512 + v] = val;
        }
    }
}

// ---------------- K5p: panel factor+solve for panel p (c0 = 32p) ----------------
// ROUND-11 FORM (reverted): the serial 32-step per-thread solves are hidden
// by 16-wave TLP; the round-12 "parallel multiply" rewrite doubled the FLOPs
// and was throughput-bound on 8 CUs (+9us/dispatch). Keep serial + TLP.
#define RSTP 484
#define LSTP 233

__global__ __launch_bounds__(1024, 4) void k5p_panel(float* __restrict__ aug, int c0) {
    __shared__ __align__(16) float R[32 * RSTP];
    __shared__ float Ls[32 * LSTP];
    __shared__ __align__(16) float Dg[32 * 33];
    __shared__ float invd[32];
    int b = blockIdx.x, tid = threadIdx.x;
    float* A = aug + (size_t)b * 256 * 512;
    int r5 = tid >> 5, c5 = tid & 31;
    int WR = 480 - c0;
    int W2 = 224 - c0;

    Dg[r5 * 33 + c5] = A[(c0 + r5) * 512 + c0 + c5];
    __syncthreads();
    if (tid < 32) {
        float u[32];
        #pragma unroll
        for (int c = 0; c < 32; c++) u[c] = Dg[tid * 33 + c];
        for (int j = 0; j < 31; j++) {
            float pv = __shfl(u[j], j);
            float f = u[j] / pv;
            #pragma unroll
            for (int c = 0; c < 32; c++) {
                if (c > j) {
                    float ujc = __shfl(u[c], j);
                    if (tid > j) u[c] -= f * ujc;
                }
            }
            if (tid > j) u[j] = f;
        }
        #pragma unroll
        for (int c = 0; c < 32; c++) Dg[tid * 33 + c] = u[c];
        invd[tid] = 1.0f / u[tid];
    }
    for (int cc = c5; cc < WR; cc += 32)
        R[r5 * RSTP + cc] = A[(c0 + r5) * 512 + c0 + 32 + cc];
    for (int row = r5; row < W2; row += 32)
        Ls[c5 * LSTP + row] = A[(c0 + 32 + row) * 512 + c0 + c5];
    __syncthreads();
    A[(c0 + r5) * 512 + c0 + c5] = Dg[r5 * 33 + c5];
    if (tid < WR) {
        float y[32];
        #pragma unroll
        for (int j = 0; j < 32; j++) {
            float s = R[j * RSTP + tid];
            #pragma unroll
            for (int m = 0; m < 32; m++)
                if (m < j) s -= Dg[j * 33 + m] * y[m];
            y[j] = s;
        }
        #pragma unroll
        for (int j = 0; j < 32; j++)
            A[(c0 + j) * 512 + c0 + 32 + tid] = y[j];
    }
    if (tid >= 512 && tid < 512 + W2) {
        int row = tid - 512;
        float l[32];
        #pragma unroll
        for (int j = 0; j < 32; j++) {
            float s = Ls[j * LSTP + row];
            #pragma unroll
            for (int m = 0; m < 32; m++)
                if (m < j) s -= l[m] * Dg[m * 33 + j];
            l[j] = s * invd[j];
        }
        #pragma unroll
        for (int j = 0; j < 32; j++)
            Ls[j * LSTP + row] = l[j];
    }
    __syncthreads();
    for (int row = r5; row < W2; row += 32)
        A[(c0 + 32 + row) * 512 + c0 + c5] = Ls[c5 * LSTP + row];
}

// ---------------- K5t: trailing update [A22|Z] -= L21 * [U12|Y] ----------------
__global__ __launch_bounds__(256) void k5t_trail(float* __restrict__ aug, int c0) {
    __shared__ __align__(16) float Lt[32][36];
    __shared__ __align__(16) float Ut[32][36];
    int b = blockIdx.z, tid = threadIdx.x;
    float* A = aug + (size_t)b * 256 * 512;
    int r0  = c0 + 32 + blockIdx.x * 32;
    int cc0 = c0 + 32 + blockIdx.y * 32;
    int lr = tid >> 3, lc = (tid & 7) * 4;
    *(float4*)&Lt[lr][lc] = *(const float4*)&A[(size_t)(r0 + lr) * 512 + c0 + lc];
    *(float4*)&Ut[lr][lc] = *(const float4*)&A[(size_t)(c0 + lr) * 512 + cc0 + lc];
    __syncthreads();
    float* gp = &A[(size_t)(r0 + lr) * 512 + cc0 + lc];
    float4 acc = *(const float4*)gp;
    #pragma unroll
    for (int k = 0; k < 32; k++) {
        float lv = Lt[lr][k];
        float4 uv = *(const float4*)&Ut[k][lc];
        acc.x -= lv * uv.x;
        acc.y -= lv * uv.y;
        acc.z -= lv * uv.z;
        acc.w -= lv * uv.w;
    }
    *(float4*)gp = acc;
}

// ---------------- K5I: invU[b][p] = inv(U_pp) (32x32 upper) ----------------
__global__ __launch_bounds__(64) void k5i_invu(const float* __restrict__ aug,
                                               float* __restrict__ invU) {
    __shared__ float Dg[32 * 33];
    __shared__ float invd[32];
    int p = blockIdx.x, b = blockIdx.y, tid = threadIdx.x;
    const float* A = aug + (size_t)b * 256 * 512;
    int c0 = 32 * p;
    for (int i = tid; i < 1024; i += 64)
        Dg[(i >> 5) * 33 + (i & 31)] = A[(size_t)(c0 + (i >> 5)) * 512 + c0 + (i & 31)];
    __syncthreads();
    if (tid < 32) invd[tid] = 1.0f / Dg[tid * 33 + tid];
    __syncthreads();
    if (tid < 32) {
        int c = tid;
        float x[32];
        #pragma unroll
        for (int j = 31; j >= 0; j--) {
            float s = (j == c) ? 1.0f : 0.0f;
            #pragma unroll
            for (int m = 0; m < 32; m++)
                if (m > j) s -= Dg[j * 33 + m] * x[m];
            x[j] = s * invd[j];
        }
        float* op = invU + (size_t)(b * 8 + p) * 1024;
        #pragma unroll
        for (int j = 0; j < 32; j++) op[j * 32 + c] = x[j];
    }
}

// ---------------- K5s: backward sweep via X = invU * Z, 32 cols/block ----------------
#define ZST  36
#define LBST 36

__global__ __launch_bounds__(512, 2) void k5s_solve(float* __restrict__ aug,
                                                    const float* __restrict__ invU) {
    __shared__ __align__(16) float Zs[256 * ZST];
    __shared__ __align__(16) float Lb[224 * LBST];
    __shared__ __align__(16) float Dg[32 * 33];
    int b = blockIdx.y, tid = threadIdx.x;
    float* A = aug + (size_t)b * 256 * 512;
    int cb = blockIdx.x * 32;
    int c = tid & 31, g = tid >> 5;       // g in 0..15
    int rr = tid >> 5, cc = tid & 31;

    for (int r = g; r < 256; r += 16)
        Zs[r * ZST + c] = A[r * 512 + 256 + cb + c];

    for (int p = 7; p >= 0; p--) {
        int c0 = 32 * p, na = c0;
        for (int i = tid; i < 1024; i += 512)
            Dg[(i >> 5) * 33 + (i & 31)] = invU[(size_t)(b * 8 + p) * 1024 + i];
        for (int r = rr; r < na; r += 16)
            Lb[r * LBST + cc] = A[r * 512 + c0 + cc];
        __syncthreads();
        float z[32];
        #pragma unroll
        for (int m = 0; m < 32; m++) z[m] = Zs[(c0 + m) * ZST + c];
        float xr[2];
        #pragma unroll
        for (int r2 = 0; r2 < 2; r2++) {
            const float* dr = &Dg[(g * 2 + r2) * 33];
            float s0 = 0.f, s1 = 0.f, s2 = 0.f, s3 = 0.f;
            #pragma unroll
            for (int m = 0; m < 32; m += 4) {
                s0 += dr[m + 0] * z[m + 0];
                s1 += dr[m + 1] * z[m + 1];
                s2 += dr[m + 2] * z[m + 2];
                s3 += dr[m + 3] * z[m + 3];
            }
            xr[r2] = (s0 + s1) + (s2 + s3);
        }
        __syncthreads();
        #pragma unroll
        for (int r2 = 0; r2 < 2; r2++)
            Zs[(c0 + g * 2 + r2) * ZST + c] = xr[r2];
        __syncthreads();
        if (na > 0) {
            float zx[32];
            #pragma unroll
            for (int k = 0; k < 32; k++) zx[k] = Zs[(c0 + k) * ZST + c];
            for (int r = g; r < na; r += 16) {
                const float* lp = &Lb[r * LBST];
                float a0 = 0.f, a1 = 0.f, a2 = 0.f, a3 = 0.f;
                #pragma unroll
                for (int k = 0; k < 32; k += 4) {
                    float4 lv = *(const float4*)(lp + k);
                    a0 += lv.x * zx[k + 0];
                    a1 += lv.y * zx[k + 1];
                    a2 += lv.z * zx[k + 2];
                    a3 += lv.w * zx[k + 3];
                }
                Zs[r * ZST + c] -= (a0 + a1) + (a2 + a3);
            }
        }
        __syncthreads();
    }

    for (int r = g; r < 256; r += 16)
        A[r * 512 + 256 + cb + c] = Zs[r * ZST + c];
}

// ---------------- K6: W[f][e] = sum_y Yc[y][f] * M1[y][e] / 256 ----------------
__global__ __launch_bounds__(256) void k6_w(const float* __restrict__ Yc,
                                            const float* __restrict__ aug,
                                            float* __restrict__ W) {
    __shared__ float As[16][68];
    __shared__ float Bs[16][68];
    int tid = threadIdx.x;
    int m0 = blockIdx.x * 64, n0 = blockIdx.y * 64, b = blockIdx.z;
    const float* Ycb = Yc + (size_t)b * YD * ENSN;
    const float* augb = aug + (size_t)b * YD * 512;
    int tr = tid >> 4, tc = tid & 15;
    float acc[4][4];
    #pragma unroll
    for (int i = 0; i < 4; i++)
        #pragma unroll
        for (int j = 0; j < 4; j++) acc[i][j] = 0.f;
    int c = tid & 63, kr0 = tid >> 6;
    for (int k0 = 0; k0 < YD; k0 += 16) {
        #pragma unroll
        for (int p = 0; p < 4; p++) {
            int kk = kr0 + p * 4;
            As[kk][c] = Ycb[(k0 + kk) * ENSN + m0 + c];
            Bs[kk][c] = augb[(k0 + kk) * 512 + 256 + n0 + c];
        }
        __syncthreads();
        #pragma unroll
        for (int kk = 0; kk < 16; kk++) {
            float4 a = *(const float4*)&As[kk][tr * 4];
            float4 bb = *(const float4*)&Bs[kk][tc * 4];
            float af[4] = {a.x, a.y, a.z, a.w};
            float bf[4] = {bb.x, bb.y, bb.z, bb.w};
            #pragma unroll
            for (int i = 0; i < 4; i++)
                #pragma unroll
                for (int j = 0; j < 4; j++) acc[i][j] += af[i] * bf[j];
        }
        __syncthreads();
    }
    float* Wb = W + (size_t)b * ENSN * ENSN;
    #pragma unroll
    for (int i = 0; i < 4; i++)
        #pragma unroll
        for (int j = 0; j < 4; j++)
            Wb[(m0 + tr * 4 + i) * ENSN + n0 + tc * 4 + j] = acc[i][j] * (1.0f / ENSN);
}

// ---------------- KW_W: W[f][e] -> Wt_hi/lo[e][f] bf16 (split, transposed) ----------------
__global__ __launch_bounds__(256) void kw_w(const float* __restrict__ W,
                                            short* __restrict__ Wthi,
                                            short* __restrict__ Wtlo) {
    __shared__ float T[64][65];
    int f0 = blockIdx.x * 64, e0 = blockIdx.y * 64, b = blockIdx.z;
    const float* Wb = W + (size_t)b * ENSN * ENSN;
    int tid = threadIdx.x;
    int c = tid & 63, g = tid >> 6;
    #pragma unroll
    for (int p = 0; p < 16; p++)
        T[g + p * 4][c] = Wb[(size_t)(f0 + g + p * 4) * ENSN + e0 + c];
    __syncthreads();
    #pragma unroll
    for (int p = 0; p < 16; p++) {
        int ee = g + p * 4;
        float v = T[c][ee];   // = W[f0+c][e0+ee]
        unsigned short h = f2bf_rne(v);
        float hf = __uint_as_float(((unsigned)h) << 16);
        unsigned short l2 = f2bf_rne(v - hf);
        size_t o = (size_t)b * ENSN * ENSN + (size_t)(e0 + ee) * ENSN + f0 + c;
        Wthi[o] = (short)h;
        Wtlo[o] = (short)l2;
    }
}

// ---------------- K7M: out = E + Wt^T-style MFMA update ----------------
#define WST 36
#define XST 36

__global__ __launch_bounds__(512, 2) void k7m_update(const float* __restrict__ E,
                                                     const short* __restrict__ Wthi,
                                                     const short* __restrict__ Wtlo,
                                                     const float* __restrict__ xm,
                                                     float* __restrict__ out) {
    __shared__ __align__(16) short Ahi[256 * WST];
    __shared__ __align__(16) short Alo[256 * WST];
    __shared__ __align__(16) short Bhi[64 * XST];
    __shared__ __align__(16) short Blo[64 * XST];
    __shared__ float xs[64];
    int tid = threadIdx.x;
    int lane = tid & 63;
    int w = tid >> 6;
    int x0 = blockIdx.x * 64;
    int b = blockIdx.y;
    const short* Whb = Wthi + (size_t)b * ENSN * ENSN;
    const short* Wlb = Wtlo + (size_t)b * ENSN * ENSN;
    const float* Eb = E + (size_t)b * ENSN * XDIM;
    if (tid < 64) xs[tid] = xm[b * XDIM + x0 + tid];
    __syncthreads();
    int wr = (w & 3) * 64;    // wave M offset (e)
    int wc = (w >> 2) * 32;   // wave N offset (x)
    float4v acc[8];
    #pragma unroll
    for (int i = 0; i < 8; i++) acc[i] = (float4v){0.f, 0.f, 0.f, 0.f};
    int fr = lane & 15, fg = lane >> 4;
    int ae = tid >> 2, ach = (tid & 3) * 8;   // A stage: 2 rows of 128 e
    int bx = tid & 63, bkq = tid >> 6;        // B stage: 4 k per thread

    for (int s = 0; s < 8; s++) {
        int k0 = s * 32;
        #pragma unroll
        for (int h = 0; h < 2; h++) {
            int e = ae + h * 128;
            *(short8v*)&Ahi[e * WST + ach] = *(const short8v*)&Whb[(size_t)e * ENSN + k0 + ach];
            *(short8v*)&Alo[e * WST + ach] = *(const short8v*)&Wlb[(size_t)e * ENSN + k0 + ach];
        }
        short4v hi4, lo4;
        #pragma unroll
        for (int j = 0; j < 4; j++) {
            float v = Eb[(size_t)(k0 + bkq * 4 + j) * XDIM + x0 + bx] - xs[bx];
            unsigned short h = f2bf_rne(v);
            float hf = __uint_as_float(((unsigned)h) << 16);
            unsigned short l2 = f2bf_rne(v - hf);
            hi4[j] = (short)h; lo4[j] = (short)l2;
        }
        *(short4v*)&Bhi[bx * XST + bkq * 4] = hi4;
        *(short4v*)&Blo[bx * XST + bkq * 4] = lo4;
        __syncthreads();
        short8v ah[4], al[4], bhf[2], blf[2];
        #pragma unroll
        for (int ti = 0; ti < 4; ti++) {
            ah[ti] = *(const short8v*)&Ahi[(wr + ti * 16 + fr) * WST + fg * 8];
            al[ti] = *(const short8v*)&Alo[(wr + ti * 16 + fr) * WST + fg * 8];
        }
        #pragma unroll
        for (int tj = 0; tj < 2; tj++) {
            bhf[tj] = *(const short8v*)&Bhi[(wc + tj * 16 + fr) * XST + fg * 8];
            blf[tj] = *(const short8v*)&Blo[(wc + tj * 16 + fr) * XST + fg * 8];
        }
        #pragma unroll
        for (int ti = 0; ti < 4; ti++)
            #pragma unroll
            for (int tj = 0; tj < 2; tj++) {
                int a = ti * 2 + tj;
                acc[a] = __builtin_amdgcn_mfma_f32_16x16x32_bf16(ah[ti], bhf[tj], acc[a], 0, 0, 0);
                acc[a] = __builtin_amdgcn_mfma_f32_16x16x32_bf16(ah[ti], blf[tj], acc[a], 0, 0, 0);
                acc[a] = __builtin_amdgcn_mfma_f32_16x16x32_bf16(al[ti], bhf[tj], acc[a], 0, 0, 0);
            }
        __syncthreads();
    }
    #pragma unroll
    for (int ti = 0; ti < 4; ti++)
        #pragma unroll
        for (int tj = 0; tj < 2; tj++)
            #pragma unroll
            for (int q = 0; q < 4; q++) {
                int e = wr + ti * 16 + fg * 4 + q;
                int x = x0 + wc + tj * 16 + fr;
                size_t idx = (size_t)(b * ENSN + e) * XDIM + x;
                out[idx] = E[idx] + acc[ti * 2 + tj][q];
            }
}

extern "C" void kernel_launch(void* const* d_in, const int* in_sizes, int n_in,
                              void* d_out, int out_size, void* d_ws, size_t ws_size,
                              hipStream_t stream) {
    const float* Ens   = (const float*)d_in[0];  // [8,256,8192]
    const float* H     = (const float*)d_in[1];  // [8192,256]
    const float* ytm   = (const float*)d_in[2];  // [1,256]
    const float* ystd  = (const float*)d_in[3];  // [1,256]
    const float* noise = (const float*)d_in[4];  // [8,256,256]
    float* out = (float*)d_out;
    float* ws  = (float*)d_ws;

    float* Y   = ws + OFF_Y;
    float* Yc  = ws + OFF_YC;
    float* aug = ws + OFF_AUG;
    float* W   = ws + OFF_W;
    float* xm  = ws + OFF_XM;
    // bf16-split transposed H (Yc/aug span; dead once k2m finishes)
    short* Hthi = (short*)(ws + 524288);    // 256x8192 bf16
    short* Htlo = (short*)(ws + 1572864);   // 256x8192 bf16
    // bf16-split transposed W (Y span; Y is dead after k3)
    short* Wthi = (short*)(ws + 0);         // 8x256x256 bf16 = 262144 floats
    short* Wtlo = (short*)(ws + 262144);    // 8x256x256 bf16
    // invU in the W region (dead until k6 writes W): 8*8*1024 = 65536 floats
    float* invU = ws + OFF_W;

    hipMemsetAsync(Y, 0, (size_t)2048 * 256 * sizeof(float), stream);

    k1_colmean<<<dim3(XDIM / 256, BATCH), 256, 0, stream>>>(Ens, xm);
    kc_h<<<dim3(XDIM / 64, YD / 64), 256, 0, stream>>>(H, Hthi, Htlo);
    k2m_ygemm<<<dim3(2048 / 64, 16), 512, 0, stream>>>(Ens, Hthi, Htlo, Y);
    k3_center<<<dim3(4, BATCH), 256, 0, stream>>>(Y, ytm, ystd, noise, Yc, aug);
    k4_cyy<<<dim3(4, 4, BATCH), 256, 0, stream>>>(Yc, ystd, aug);
    for (int p = 0; p < 8; p++) {
        k5p_panel<<<dim3(BATCH), 1024, 0, stream>>>(aug, 32 * p);
        if (p < 7)
            k5t_trail<<<dim3(7 - p, 15 - p, BATCH), 256, 0, stream>>>(aug, 32 * p);
    }
    k5i_invu<<<dim3(8, BATCH), 64, 0, stream>>>(aug, invU);
    k5s_solve<<<dim3(8, BATCH), 512, 0, stream>>>(aug, invU);
    k6_w<<<dim3(4, 4, BATCH), 256, 0, stream>>>(Yc, aug, W);
    kw_w<<<dim3(4, 4, BATCH), 256, 0, stream>>>(W, Wthi, Wtlo);
    k7m_update<<<dim3(XDIM / 64, BATCH), 512, 0, stream>>>(Ens, Wthi, Wtlo, xm, out);
}